// Round 1
// baseline (321.059 us; speedup 1.0000x reference)
//
#include <hip/hip_runtime.h>

// Problem dims (from reference setup_inputs): T=256, B=128, I=512, H=512
#define T_STEPS 256
#define B_DIM   128
#define I_DIM   512
#define H_DIM   512
#define M_DIM   (T_STEPS * B_DIM)   // 32768 rows of the flattened GEMM

// GEMM tiling
#define BM 128
#define BN 128
#define BK 32

// h[m][n] = sum_k x[m][k] * W[n][k] + b[n]
// A (x) is [M][K] row-major, Bw (W) is [N][K] row-major -> both K-major.
//
// LDS layout: k-major [BK][128] floats, NO pad. Bank conflicts are killed by an
// XOR swizzle at float4 granularity: physical_blk = orig_blk ^ rho(k), with
// rho(k) = (k>>2)&7.
//  - staging writes: each thread stages k = lk..lk+3 where lk=(tid&7)*4, so
//    rho = tid&7 is thread-constant; write bank = ((blk^rho)&7)*4 + (r&3)
//    -> 2-way across a wave (free, m136).
//  - a-reads (blocks ty*2, ty*2+1): 4 distinct bank-groups/wave, conflict-free.
//  - b-reads use a SPLIT fragment (cols tx*4 and 64+tx*4): blocks tx and 16+tx
//    XOR rho -> 2-way (free). The old tx*8 mapping was a 4-way conflict.
__global__ __launch_bounds__(256, 3) void gemm_bias_f32(
    const float* __restrict__ A,
    const float* __restrict__ Bw,
    const float* __restrict__ bias,
    float* __restrict__ C)
{
    __shared__ float As[BK * BM];   // 16 KB
    __shared__ float Bs[BK * BN];   // 16 KB

    const int tid = threadIdx.x;
    const int tx  = tid & 15;   // n direction (16 threads)
    const int ty  = tid >> 4;   // m direction (16 threads)
    const int m0  = blockIdx.y * BM;
    const int n0  = blockIdx.x * BN;

    float acc[8][8];
    #pragma unroll
    for (int i = 0; i < 8; i++)
        #pragma unroll
        for (int j = 0; j < 8; j++)
            acc[i][j] = 0.0f;

    // Tile-staging mapping: each thread loads 4x float4 from A and Bw.
    const int lrow = tid >> 3;        // 0..31 (row within 32-row slab)
    const int lk   = (tid & 7) * 4;   // k offset 0,4,...,28
    const int q    = tid & 7;         // swizzle rho for this thread's 4 k-rows

    const float* Aptr = A  + (size_t)(m0 + lrow) * I_DIM + lk;
    const float* Bptr = Bw + (size_t)(n0 + lrow) * I_DIM + lk;

    for (int k0 = 0; k0 < I_DIM; k0 += BK) {
        float4 av[4], bv[4];
        #pragma unroll
        for (int p = 0; p < 4; p++) {
            av[p] = *(const float4*)(Aptr + (size_t)(p * 32) * I_DIM + k0);
            bv[p] = *(const float4*)(Bptr + (size_t)(p * 32) * I_DIM + k0);
        }

        __syncthreads();   // protect prior iteration's LDS reads

        #pragma unroll
        for (int p = 0; p < 4; p++) {
            const int r    = lrow + p * 32;
            const int base = (((r >> 2) ^ q) << 2) + (r & 3);  // swizzled col
            As[(lk + 0) * BM + base] = av[p].x;
            As[(lk + 1) * BM + base] = av[p].y;
            As[(lk + 2) * BM + base] = av[p].z;
            As[(lk + 3) * BM + base] = av[p].w;
            Bs[(lk + 0) * BN + base] = bv[p].x;
            Bs[(lk + 1) * BN + base] = bv[p].y;
            Bs[(lk + 2) * BN + base] = bv[p].z;
            Bs[(lk + 3) * BN + base] = bv[p].w;
        }

        __syncthreads();

        const float4* As4 = (const float4*)As;
        const float4* Bs4 = (const float4*)Bs;
        for (int k = 0; k < BK; k++) {
            const int rho = (k >> 2) & 7;
            // a: rows m0 + ty*8 .. ty*8+7  (orig blocks ty*2, ty*2+1)
            float4 a0 = As4[k * (BM / 4) + ((ty * 2)     ^ rho)];
            float4 a1 = As4[k * (BM / 4) + ((ty * 2 + 1) ^ rho)];
            // b: cols n0 + tx*4..+3 and n0 + 64 + tx*4..+3 (orig blocks tx, 16+tx)
            float4 b0 = Bs4[k * (BN / 4) + (tx        ^ rho)];
            float4 b1 = Bs4[k * (BN / 4) + ((16 + tx) ^ rho)];
            float a[8] = {a0.x, a0.y, a0.z, a0.w, a1.x, a1.y, a1.z, a1.w};
            float b[8] = {b0.x, b0.y, b0.z, b0.w, b1.x, b1.y, b1.z, b1.w};
            #pragma unroll
            for (int i = 0; i < 8; i++)
                #pragma unroll
                for (int j = 0; j < 8; j++)
                    acc[i][j] = fmaf(a[i], b[j], acc[i][j]);
        }
    }

    // Epilogue: add bias, write two float4s per row (split-col fragment)
    float4 bc0 = *(const float4*)(bias + n0 + tx * 4);
    float4 bc1 = *(const float4*)(bias + n0 + 64 + tx * 4);

    #pragma unroll
    for (int i = 0; i < 8; i++) {
        const int m = m0 + ty * 8 + i;
        float4 o0, o1;
        o0.x = acc[i][0] + bc0.x;
        o0.y = acc[i][1] + bc0.y;
        o0.z = acc[i][2] + bc0.z;
        o0.w = acc[i][3] + bc0.w;
        o1.x = acc[i][4] + bc1.x;
        o1.y = acc[i][5] + bc1.y;
        o1.z = acc[i][6] + bc1.z;
        o1.w = acc[i][7] + bc1.w;
        float* cp = C + (size_t)m * H_DIM + n0;
        *(float4*)(cp + tx * 4)      = o0;
        *(float4*)(cp + 64 + tx * 4) = o1;
    }
}

// LIF scan over T. One thread per neuron (b, j); n = B*H neurons.
// v <- v/2 + h_t ; s = (v >= 1) ; v <- s ? 0 : v
//
// Only 1024 waves exist (grid-limited, 1 wave/SIMD) -> latency must be hidden
// in-thread. Software pipeline: two named 32-deep buffers (static indexing
// only), next batch's 32 loads issued BEFORE the current dependent chain runs,
// so ~8 KB/wave stays in flight continuously. h is L3-resident (written by the
// GEMM just before). Nontemporal stores keep `out` from evicting h.
#define SCAN_U 32
__global__ __launch_bounds__(256) void lif_scan(
    const float* __restrict__ h,
    float* __restrict__ out)
{
    const int n   = B_DIM * H_DIM;   // 65536
    const int idx = blockIdx.x * 256 + threadIdx.x;
    const float* hp = h + idx;
    float* op = out + idx;

    float bufA[SCAN_U], bufB[SCAN_U];

    #pragma unroll
    for (int i = 0; i < SCAN_U; i++)
        bufA[i] = hp[(size_t)i * n];

    float v = 0.0f;
    for (int t0 = 0; t0 < T_STEPS; t0 += 2 * SCAN_U) {
        // prefetch batch B (t0+U .. t0+2U-1) before chewing on A
        #pragma unroll
        for (int i = 0; i < SCAN_U; i++)
            bufB[i] = hp[(size_t)(t0 + SCAN_U + i) * n];

        #pragma unroll
        for (int i = 0; i < SCAN_U; i++) {
            v = fmaf(0.5f, v, bufA[i]);
            const bool fire = (v >= 1.0f);
            __builtin_nontemporal_store(fire ? 1.0f : 0.0f,
                                        op + (size_t)(t0 + i) * n);
            v = fire ? 0.0f : v;
        }

        // prefetch next batch A (t0+2U .. t0+3U-1)
        if (t0 + 2 * SCAN_U < T_STEPS) {
            #pragma unroll
            for (int i = 0; i < SCAN_U; i++)
                bufA[i] = hp[(size_t)(t0 + 2 * SCAN_U + i) * n];
        }

        #pragma unroll
        for (int i = 0; i < SCAN_U; i++) {
            v = fmaf(0.5f, v, bufB[i]);
            const bool fire = (v >= 1.0f);
            __builtin_nontemporal_store(fire ? 1.0f : 0.0f,
                                        op + (size_t)(t0 + SCAN_U + i) * n);
            v = fire ? 0.0f : v;
        }
    }
}

extern "C" void kernel_launch(void* const* d_in, const int* in_sizes, int n_in,
                              void* d_out, int out_size, void* d_ws, size_t ws_size,
                              hipStream_t stream) {
    const float* x = (const float*)d_in[0];   // (T, B, I) fp32
    const float* W = (const float*)d_in[1];   // (H, I)    fp32
    const float* b = (const float*)d_in[2];   // (H,)      fp32
    float* out = (float*)d_out;               // (T, B, H) fp32 spikes
    float* h   = (float*)d_ws;                // (T*B, H) fp32 scratch = 64 MB

    dim3 grid(H_DIM / BN, M_DIM / BM);        // (4, 256)
    gemm_bias_f32<<<grid, 256, 0, stream>>>(x, W, b, h);

    lif_scan<<<(B_DIM * H_DIM) / 256, 256, 0, stream>>>(h, out);
}